// Round 1
// baseline (1562.023 us; speedup 1.0000x reference)
//
#include <hip/hip_runtime.h>
#include <math.h>

#define BB 512
#define TM1 16
#define TT 17
#define RR 256
#define HIDN 512

// workspace layout (floats)
#define WS_STATS 0                       // 32 floats: sum[16], sumsq[16]
#define WS_SPREV 32                      // 512*256
#define WS_H0 (32 + 512*256)             // 512*512
#define WS_H1 (WS_H0 + 512*512)          // 512*512

__global__ void zero_ws_k(float* __restrict__ p, int n) {
  int i = blockIdx.x * blockDim.x + threadIdx.x;
  int stride = gridDim.x * blockDim.x;
  for (; i < n; i += stride) p[i] = 0.0f;
}

// ---------------- Encoder pass A: conv + channel sum/sumsq ----------------
__global__ __launch_bounds__(256) void enc_conv_stats(const float* __restrict__ x,
                                                      const float* __restrict__ cw,
                                                      float* __restrict__ stats) {
  __shared__ float imgp[2 * 66 * 66];
  const int b = blockIdx.x, tid = threadIdx.x;
  for (int i = tid; i < 2 * 66 * 66; i += 256) imgp[i] = 0.0f;
  __syncthreads();
  const float* xb = x + b * 8192;
  for (int i = tid; i < 8192; i += 256) {
    int ci = i >> 12, rem = i & 4095, y = rem >> 6, xx = rem & 63;
    imgp[ci * 4356 + (y + 1) * 66 + (xx + 1)] = xb[i];
  }
  __syncthreads();

  for (int c4 = 0; c4 < 4; ++c4) {
    float w0[18], w1[18], w2[18], w3[18];
#pragma unroll
    for (int k = 0; k < 18; ++k) {
      w0[k] = cw[(c4 * 4 + 0) * 18 + k];
      w1[k] = cw[(c4 * 4 + 1) * 18 + k];
      w2[k] = cw[(c4 * 4 + 2) * 18 + k];
      w3[k] = cw[(c4 * 4 + 3) * 18 + k];
    }
    float s0 = 0, s1 = 0, s2 = 0, s3 = 0, q0 = 0, q1 = 0, q2 = 0, q3 = 0;
    for (int p = tid; p < 4096; p += 256) {
      int y = p >> 6, xx = p & 63;
      float v[18];
#pragma unroll
      for (int ci = 0; ci < 2; ++ci)
#pragma unroll
        for (int dy = 0; dy < 3; ++dy)
#pragma unroll
          for (int dx = 0; dx < 3; ++dx)
            v[ci * 9 + dy * 3 + dx] = imgp[ci * 4356 + (y + dy) * 66 + (xx + dx)];
      float a0 = 0, a1 = 0, a2 = 0, a3 = 0;
#pragma unroll
      for (int k = 0; k < 18; ++k) {
        a0 = fmaf(w0[k], v[k], a0);
        a1 = fmaf(w1[k], v[k], a1);
        a2 = fmaf(w2[k], v[k], a2);
        a3 = fmaf(w3[k], v[k], a3);
      }
      s0 += a0; q0 = fmaf(a0, a0, q0);
      s1 += a1; q1 = fmaf(a1, a1, q1);
      s2 += a2; q2 = fmaf(a2, a2, q2);
      s3 += a3; q3 = fmaf(a3, a3, q3);
    }
#pragma unroll
    for (int off = 32; off >= 1; off >>= 1) {
      s0 += __shfl_down(s0, off); q0 += __shfl_down(q0, off);
      s1 += __shfl_down(s1, off); q1 += __shfl_down(q1, off);
      s2 += __shfl_down(s2, off); q2 += __shfl_down(q2, off);
      s3 += __shfl_down(s3, off); q3 += __shfl_down(q3, off);
    }
    if ((tid & 63) == 0) {
      atomicAdd(&stats[c4 * 4 + 0], s0); atomicAdd(&stats[16 + c4 * 4 + 0], q0);
      atomicAdd(&stats[c4 * 4 + 1], s1); atomicAdd(&stats[16 + c4 * 4 + 1], q1);
      atomicAdd(&stats[c4 * 4 + 2], s2); atomicAdd(&stats[16 + c4 * 4 + 2], q2);
      atomicAdd(&stats[c4 * 4 + 3], s3); atomicAdd(&stats[16 + c4 * 4 + 3], q3);
    }
  }
}

// ---- Encoder pass B: conv + BN + relu + maxpool + avgpool + FC -> s0 ----
__global__ __launch_bounds__(256) void enc_finish(const float* __restrict__ x,
                                                  const float* __restrict__ cw,
                                                  const float* __restrict__ stats,
                                                  const float* __restrict__ gamma,
                                                  const float* __restrict__ beta,
                                                  const float* __restrict__ fcw,
                                                  const float* __restrict__ fcb,
                                                  float* __restrict__ sprev,
                                                  float* __restrict__ out) {
  __shared__ float imgp[2 * 66 * 66];
  __shared__ float red[4][16];
  __shared__ float plds[16];
  const int b = blockIdx.x, tid = threadIdx.x;
  for (int i = tid; i < 2 * 66 * 66; i += 256) imgp[i] = 0.0f;
  __syncthreads();
  const float* xb = x + b * 8192;
  for (int i = tid; i < 8192; i += 256) {
    int ci = i >> 12, rem = i & 4095, y = rem >> 6, xx = rem & 63;
    imgp[ci * 4356 + (y + 1) * 66 + (xx + 1)] = xb[i];
  }
  __syncthreads();

  const float invN = 1.0f / (512.0f * 4096.0f);
  const int wv = tid >> 6;

  for (int c4 = 0; c4 < 4; ++c4) {
    float w0[18], w1[18], w2[18], w3[18];
#pragma unroll
    for (int k = 0; k < 18; ++k) {
      w0[k] = cw[(c4 * 4 + 0) * 18 + k];
      w1[k] = cw[(c4 * 4 + 1) * 18 + k];
      w2[k] = cw[(c4 * 4 + 2) * 18 + k];
      w3[k] = cw[(c4 * 4 + 3) * 18 + k];
    }
    float sc0, sc1, sc2, sc3, sh0, sh1, sh2, sh3;
    {
      int c = c4 * 4 + 0; float m = stats[c] * invN; float var = stats[16 + c] * invN - m * m;
      float isd = rsqrtf(var + 1e-5f); sc0 = gamma[c] * isd; sh0 = beta[c] - m * sc0;
      c = c4 * 4 + 1; m = stats[c] * invN; var = stats[16 + c] * invN - m * m;
      isd = rsqrtf(var + 1e-5f); sc1 = gamma[c] * isd; sh1 = beta[c] - m * sc1;
      c = c4 * 4 + 2; m = stats[c] * invN; var = stats[16 + c] * invN - m * m;
      isd = rsqrtf(var + 1e-5f); sc2 = gamma[c] * isd; sh2 = beta[c] - m * sc2;
      c = c4 * 4 + 3; m = stats[c] * invN; var = stats[16 + c] * invN - m * m;
      isd = rsqrtf(var + 1e-5f); sc3 = gamma[c] * isd; sh3 = beta[c] - m * sc3;
    }
    float p0 = 0, p1 = 0, p2 = 0, p3 = 0;
    for (int q = tid; q < 1024; q += 256) {
      int py = q >> 5, px = q & 31;
      float m0 = 0, m1 = 0, m2 = 0, m3 = 0;
#pragma unroll
      for (int sy = 0; sy < 2; ++sy)
#pragma unroll
        for (int sx = 0; sx < 2; ++sx) {
          int y = 2 * py + sy, xx = 2 * px + sx;
          float v[18];
#pragma unroll
          for (int ci = 0; ci < 2; ++ci)
#pragma unroll
            for (int dy = 0; dy < 3; ++dy)
#pragma unroll
              for (int dx = 0; dx < 3; ++dx)
                v[ci * 9 + dy * 3 + dx] = imgp[ci * 4356 + (y + dy) * 66 + (xx + dx)];
          float a0 = 0, a1 = 0, a2 = 0, a3 = 0;
#pragma unroll
          for (int k = 0; k < 18; ++k) {
            a0 = fmaf(w0[k], v[k], a0);
            a1 = fmaf(w1[k], v[k], a1);
            a2 = fmaf(w2[k], v[k], a2);
            a3 = fmaf(w3[k], v[k], a3);
          }
          m0 = fmaxf(m0, fmaxf(fmaf(a0, sc0, sh0), 0.0f));
          m1 = fmaxf(m1, fmaxf(fmaf(a1, sc1, sh1), 0.0f));
          m2 = fmaxf(m2, fmaxf(fmaf(a2, sc2, sh2), 0.0f));
          m3 = fmaxf(m3, fmaxf(fmaf(a3, sc3, sh3), 0.0f));
        }
      p0 += m0; p1 += m1; p2 += m2; p3 += m3;
    }
#pragma unroll
    for (int off = 32; off >= 1; off >>= 1) {
      p0 += __shfl_down(p0, off);
      p1 += __shfl_down(p1, off);
      p2 += __shfl_down(p2, off);
      p3 += __shfl_down(p3, off);
    }
    if ((tid & 63) == 0) {
      red[wv][c4 * 4 + 0] = p0;
      red[wv][c4 * 4 + 1] = p1;
      red[wv][c4 * 4 + 2] = p2;
      red[wv][c4 * 4 + 3] = p3;
    }
  }
  __syncthreads();
  if (tid < 16)
    plds[tid] = (red[0][tid] + red[1][tid] + red[2][tid] + red[3][tid]) * (1.0f / 1024.0f);
  __syncthreads();

  float acc = fcb[tid];
#pragma unroll
  for (int c = 0; c < 16; ++c) acc = fmaf(plds[c], fcw[tid * 16 + c], acc);
  sprev[b * 256 + tid] = acc;
  out[(b * TT + 0) * 256 + tid] = acc;
}

// ------------- GRU step: gates + h_new (32x32 tile, 4 rows/thread) -------------
__global__ __launch_bounds__(256) void gru_step(const float* __restrict__ sprev,
                                                const float* __restrict__ actions,
                                                const float* __restrict__ h_in,
                                                float* __restrict__ h_out,
                                                const float* __restrict__ wih,
                                                const float* __restrict__ whh,
                                                const float* __restrict__ bih,
                                                const float* __restrict__ bhh,
                                                int t) {
  __shared__ float Ws[3 * 32 * 36];
  const int tid = threadIdx.x;
  const int tx = tid & 31, ty = tid >> 5;
  const int bx = blockIdx.x, by = blockIdx.y;
  const int j = bx * 32 + tx;

  float ar[4], az[4], axn[4], ahn[4];
  {
    float br = bih[j] + bhh[j];
    float bz = bih[512 + j] + bhh[512 + j];
    float bxnv = bih[1024 + j];
    float bhnv = bhh[1024 + j];
#pragma unroll
    for (int i = 0; i < 4; ++i) { ar[i] = br; az[i] = bz; axn[i] = bxnv; ahn[i] = bhnv; }
  }
  const float4* Ws4 = (const float4*)Ws;

  // phase 1: A = sprev (K=256), W = wih (row stride 258)
  for (int kc = 0; kc < 8; ++kc) {
    __syncthreads();
#pragma unroll
    for (int qq = 0; qq < 12; ++qq) {
      int idx = qq * 256 + tid;
      int g = idx >> 10, rem = idx & 1023, jj = rem >> 5, kk = rem & 31;
      Ws[g * 1152 + jj * 36 + kk] = wih[(g * 512 + bx * 32 + jj) * 258 + kc * 32 + kk];
    }
    __syncthreads();
#pragma unroll
    for (int k4 = 0; k4 < 8; ++k4) {
      float4 av[4];
#pragma unroll
      for (int i = 0; i < 4; ++i)
        av[i] = *(const float4*)(sprev + (by * 32 + ty + 8 * i) * 256 + kc * 32 + k4 * 4);
      float4 wr = Ws4[0 * 288 + tx * 9 + k4];
      float4 wz = Ws4[1 * 288 + tx * 9 + k4];
      float4 wn = Ws4[2 * 288 + tx * 9 + k4];
#pragma unroll
      for (int i = 0; i < 4; ++i) {
        ar[i] = fmaf(av[i].x, wr.x, ar[i]); ar[i] = fmaf(av[i].y, wr.y, ar[i]);
        ar[i] = fmaf(av[i].z, wr.z, ar[i]); ar[i] = fmaf(av[i].w, wr.w, ar[i]);
        az[i] = fmaf(av[i].x, wz.x, az[i]); az[i] = fmaf(av[i].y, wz.y, az[i]);
        az[i] = fmaf(av[i].z, wz.z, az[i]); az[i] = fmaf(av[i].w, wz.w, az[i]);
        axn[i] = fmaf(av[i].x, wn.x, axn[i]); axn[i] = fmaf(av[i].y, wn.y, axn[i]);
        axn[i] = fmaf(av[i].z, wn.z, axn[i]); axn[i] = fmaf(av[i].w, wn.w, axn[i]);
      }
    }
  }
  // u tail (x columns 256,257)
  {
    float wur = wih[j * 258 + 256], wvr = wih[j * 258 + 257];
    float wuz = wih[(512 + j) * 258 + 256], wvz = wih[(512 + j) * 258 + 257];
    float wun = wih[(1024 + j) * 258 + 256], wvn = wih[(1024 + j) * 258 + 257];
#pragma unroll
    for (int i = 0; i < 4; ++i) {
      int r = by * 32 + ty + 8 * i;
      float u0 = actions[r * (TM1 * 2) + t * 2 + 0];
      float u1 = actions[r * (TM1 * 2) + t * 2 + 1];
      ar[i] += u0 * wur + u1 * wvr;
      az[i] += u0 * wuz + u1 * wvz;
      axn[i] += u0 * wun + u1 * wvn;
    }
  }
  // phase 2: A = h_in (K=512), W = whh (row stride 512)
  for (int kc = 0; kc < 16; ++kc) {
    __syncthreads();
#pragma unroll
    for (int qq = 0; qq < 12; ++qq) {
      int idx = qq * 256 + tid;
      int g = idx >> 10, rem = idx & 1023, jj = rem >> 5, kk = rem & 31;
      Ws[g * 1152 + jj * 36 + kk] = whh[(g * 512 + bx * 32 + jj) * 512 + kc * 32 + kk];
    }
    __syncthreads();
#pragma unroll
    for (int k4 = 0; k4 < 8; ++k4) {
      float4 av[4];
#pragma unroll
      for (int i = 0; i < 4; ++i)
        av[i] = *(const float4*)(h_in + (by * 32 + ty + 8 * i) * 512 + kc * 32 + k4 * 4);
      float4 wr = Ws4[0 * 288 + tx * 9 + k4];
      float4 wz = Ws4[1 * 288 + tx * 9 + k4];
      float4 wn = Ws4[2 * 288 + tx * 9 + k4];
#pragma unroll
      for (int i = 0; i < 4; ++i) {
        ar[i] = fmaf(av[i].x, wr.x, ar[i]); ar[i] = fmaf(av[i].y, wr.y, ar[i]);
        ar[i] = fmaf(av[i].z, wr.z, ar[i]); ar[i] = fmaf(av[i].w, wr.w, ar[i]);
        az[i] = fmaf(av[i].x, wz.x, az[i]); az[i] = fmaf(av[i].y, wz.y, az[i]);
        az[i] = fmaf(av[i].z, wz.z, az[i]); az[i] = fmaf(av[i].w, wz.w, az[i]);
        ahn[i] = fmaf(av[i].x, wn.x, ahn[i]); ahn[i] = fmaf(av[i].y, wn.y, ahn[i]);
        ahn[i] = fmaf(av[i].z, wn.z, ahn[i]); ahn[i] = fmaf(av[i].w, wn.w, ahn[i]);
      }
    }
  }
  // epilogue: gates + blend
#pragma unroll
  for (int i = 0; i < 4; ++i) {
    int r = by * 32 + ty + 8 * i;
    float rg = 1.0f / (1.0f + __expf(-ar[i]));
    float zg = 1.0f / (1.0f + __expf(-az[i]));
    float xn = axn[i] + rg * ahn[i];
    xn = fminf(fmaxf(xn, -15.0f), 15.0f);
    float e = __expf(2.0f * xn);
    float ng = (e - 1.0f) / (e + 1.0f);
    float ho = h_in[r * 512 + j];
    h_out[r * 512 + j] = (1.0f - zg) * ng + zg * ho;
  }
}

// ------------------- pred FC: s_pred = relu(h @ P^T + b) -------------------
__global__ __launch_bounds__(256) void pred_step(const float* __restrict__ h,
                                                 const float* __restrict__ pw,
                                                 const float* __restrict__ pb,
                                                 float* __restrict__ out,
                                                 float* __restrict__ sprev,
                                                 int t) {
  __shared__ float Ps[32 * 36];
  const int tid = threadIdx.x, tx = tid & 31, ty = tid >> 5;
  const int bx = blockIdx.x, by = blockIdx.y;
  const int j = bx * 32 + tx;
  float a0 = 0, a1 = 0;
  const float4* Ps4 = (const float4*)Ps;
  for (int kc = 0; kc < 16; ++kc) {
    __syncthreads();
#pragma unroll
    for (int qq = 0; qq < 4; ++qq) {
      int idx = qq * 256 + tid, jj = idx >> 5, kk = idx & 31;
      Ps[jj * 36 + kk] = pw[(bx * 32 + jj) * 512 + kc * 32 + kk];
    }
    __syncthreads();
#pragma unroll
    for (int k4 = 0; k4 < 8; ++k4) {
      float4 h0v = *(const float4*)(h + (by * 16 + ty) * 512 + kc * 32 + k4 * 4);
      float4 h1v = *(const float4*)(h + (by * 16 + ty + 8) * 512 + kc * 32 + k4 * 4);
      float4 w = Ps4[tx * 9 + k4];
      a0 = fmaf(h0v.x, w.x, a0); a0 = fmaf(h0v.y, w.y, a0);
      a0 = fmaf(h0v.z, w.z, a0); a0 = fmaf(h0v.w, w.w, a0);
      a1 = fmaf(h1v.x, w.x, a1); a1 = fmaf(h1v.y, w.y, a1);
      a1 = fmaf(h1v.z, w.z, a1); a1 = fmaf(h1v.w, w.w, a1);
    }
  }
  float bias = pb[j];
  float v0 = fmaxf(a0 + bias, 0.0f), v1 = fmaxf(a1 + bias, 0.0f);
  int r0 = by * 16 + ty, r1 = r0 + 8;
  out[(r0 * TT + t + 1) * 256 + j] = v0;
  out[(r1 * TT + t + 1) * 256 + j] = v1;
  sprev[r0 * 256 + j] = v0;
  sprev[r1 * 256 + j] = v1;
}

extern "C" void kernel_launch(void* const* d_in, const int* in_sizes, int n_in,
                              void* d_out, int out_size, void* d_ws, size_t ws_size,
                              hipStream_t stream) {
  const float* x       = (const float*)d_in[0];
  const float* actions = (const float*)d_in[1];
  const float* cw      = (const float*)d_in[2];
  const float* gamma   = (const float*)d_in[3];
  const float* beta    = (const float*)d_in[4];
  const float* fcw     = (const float*)d_in[5];
  const float* fcb     = (const float*)d_in[6];
  const float* wih     = (const float*)d_in[7];
  const float* whh     = (const float*)d_in[8];
  const float* bih     = (const float*)d_in[9];
  const float* bhh     = (const float*)d_in[10];
  const float* pw      = (const float*)d_in[11];
  const float* pb      = (const float*)d_in[12];
  float* out = (float*)d_out;
  float* ws  = (float*)d_ws;

  float* stats = ws + WS_STATS;
  float* sprev = ws + WS_SPREV;
  float* hbuf0 = ws + WS_H0;
  float* hbuf1 = ws + WS_H1;

  // zero stats + sprev + h0 (atomics accumulate into stats; h0 must be 0)
  zero_ws_k<<<dim3(256), dim3(256), 0, stream>>>(ws, 32 + 512 * 256 + 512 * 512);

  enc_conv_stats<<<dim3(512), dim3(256), 0, stream>>>(x, cw, stats);
  enc_finish<<<dim3(512), dim3(256), 0, stream>>>(x, cw, stats, gamma, beta, fcw, fcb,
                                                  sprev, out);
  for (int t = 0; t < TM1; ++t) {
    float* hi = (t & 1) ? hbuf1 : hbuf0;
    float* ho = (t & 1) ? hbuf0 : hbuf1;
    gru_step<<<dim3(16, 16), dim3(256), 0, stream>>>(sprev, actions, hi, ho,
                                                     wih, whh, bih, bhh, t);
    pred_step<<<dim3(8, 32), dim3(256), 0, stream>>>(ho, pw, pb, out, sprev, t);
  }
}

// Round 3
// 382.062 us; speedup vs baseline: 4.0884x; 4.0884x over previous
//
#include <hip/hip_runtime.h>
#include <hip/hip_bf16.h>
#include <math.h>

#define TM1 16
#define TT 17

typedef __attribute__((ext_vector_type(8))) __bf16 bf16x8;
typedef __attribute__((ext_vector_type(4))) float f32x4;

// ---------------- workspace layout (float units, all 16B-aligned) ----------------
#define OFF_STATS  0          // 32 f
#define OFF_BSTATS 32         // 512*32 f
#define OFF_H0     16416      // 512*512 f
#define OFF_H1     278560     // 512*512 f
#define OFF_HB0    540704     // 512*512 bf16 (131072 f-units)
#define OFF_HB1    671776
#define OFF_SPB    802848     // 512*256 bf16 (65536 f-units)
#define OFF_WIHB   868384     // 1536*256 bf16 (196608 f-units)
#define OFF_WHHB   1064992    // 1536*512 bf16 (393216 f-units)
#define OFF_PWB    1458208    // 256*512 bf16 (65536 f-units)
// total 1523744 floats ~= 6.1 MB

__global__ void zero2_k(float* __restrict__ p1, int n1, float* __restrict__ p2, int n2) {
  int i = blockIdx.x * blockDim.x + threadIdx.x;
  int st = gridDim.x * blockDim.x;
  for (int j = i; j < n1; j += st) p1[j] = 0.0f;
  for (int j = i; j < n2; j += st) p2[j] = 0.0f;
}

// convert weights to bf16 once per launch
__global__ void prep_weights_k(const float* __restrict__ wih, const float* __restrict__ whh,
                               const float* __restrict__ pw,
                               __hip_bfloat16* __restrict__ wihb,
                               __hip_bfloat16* __restrict__ whhb,
                               __hip_bfloat16* __restrict__ pwb) {
  const int n1 = 1536 * 256, n2 = 1536 * 512, n3 = 256 * 512;
  int i = blockIdx.x * blockDim.x + threadIdx.x;
  int st = gridDim.x * blockDim.x;
  for (int j = i; j < n1 + n2 + n3; j += st) {
    if (j < n1) {
      int r = j >> 8, c = j & 255;
      wihb[j] = __float2bfloat16(wih[r * 258 + c]);
    } else if (j < n1 + n2) {
      int k = j - n1;
      whhb[k] = __float2bfloat16(whh[k]);
    } else {
      int k = j - n1 - n2;
      pwb[k] = __float2bfloat16(pw[k]);
    }
  }
}

// ---------------- Encoder pass A: conv + per-block channel sum/sumsq ----------------
__global__ __launch_bounds__(256) void enc_conv_stats(const float* __restrict__ x,
                                                      const float* __restrict__ cw,
                                                      float* __restrict__ bstats) {
  __shared__ float imgp[2 * 66 * 66];
  __shared__ float reds[4][16], redq[4][16];
  const int b = blockIdx.x, tid = threadIdx.x;
  const int wv = tid >> 6;
  for (int i = tid; i < 2 * 66 * 66; i += 256) imgp[i] = 0.0f;
  __syncthreads();
  const float* xb = x + b * 8192;
  for (int i = tid; i < 8192; i += 256) {
    int ci = i >> 12, rem = i & 4095, y = rem >> 6, xx = rem & 63;
    imgp[ci * 4356 + (y + 1) * 66 + (xx + 1)] = xb[i];
  }
  __syncthreads();

  for (int c4 = 0; c4 < 4; ++c4) {
    float w0[18], w1[18], w2[18], w3[18];
#pragma unroll
    for (int k = 0; k < 18; ++k) {
      w0[k] = cw[(c4 * 4 + 0) * 18 + k];
      w1[k] = cw[(c4 * 4 + 1) * 18 + k];
      w2[k] = cw[(c4 * 4 + 2) * 18 + k];
      w3[k] = cw[(c4 * 4 + 3) * 18 + k];
    }
    float s0 = 0, s1 = 0, s2 = 0, s3 = 0, q0 = 0, q1 = 0, q2 = 0, q3 = 0;
    for (int p = tid; p < 4096; p += 256) {
      int y = p >> 6, xx = p & 63;
      float v[18];
#pragma unroll
      for (int ci = 0; ci < 2; ++ci)
#pragma unroll
        for (int dy = 0; dy < 3; ++dy)
#pragma unroll
          for (int dx = 0; dx < 3; ++dx)
            v[ci * 9 + dy * 3 + dx] = imgp[ci * 4356 + (y + dy) * 66 + (xx + dx)];
      float a0 = 0, a1 = 0, a2 = 0, a3 = 0;
#pragma unroll
      for (int k = 0; k < 18; ++k) {
        a0 = fmaf(w0[k], v[k], a0);
        a1 = fmaf(w1[k], v[k], a1);
        a2 = fmaf(w2[k], v[k], a2);
        a3 = fmaf(w3[k], v[k], a3);
      }
      s0 += a0; q0 = fmaf(a0, a0, q0);
      s1 += a1; q1 = fmaf(a1, a1, q1);
      s2 += a2; q2 = fmaf(a2, a2, q2);
      s3 += a3; q3 = fmaf(a3, a3, q3);
    }
#pragma unroll
    for (int off = 32; off >= 1; off >>= 1) {
      s0 += __shfl_down(s0, off); q0 += __shfl_down(q0, off);
      s1 += __shfl_down(s1, off); q1 += __shfl_down(q1, off);
      s2 += __shfl_down(s2, off); q2 += __shfl_down(q2, off);
      s3 += __shfl_down(s3, off); q3 += __shfl_down(q3, off);
    }
    if ((tid & 63) == 0) {
      reds[wv][c4 * 4 + 0] = s0; redq[wv][c4 * 4 + 0] = q0;
      reds[wv][c4 * 4 + 1] = s1; redq[wv][c4 * 4 + 1] = q1;
      reds[wv][c4 * 4 + 2] = s2; redq[wv][c4 * 4 + 2] = q2;
      reds[wv][c4 * 4 + 3] = s3; redq[wv][c4 * 4 + 3] = q3;
    }
  }
  __syncthreads();
  if (tid < 16)
    bstats[b * 32 + tid] = reds[0][tid] + reds[1][tid] + reds[2][tid] + reds[3][tid];
  else if (tid < 32) {
    int c = tid - 16;
    bstats[b * 32 + tid] = redq[0][c] + redq[1][c] + redq[2][c] + redq[3][c];
  }
}

// reduce 512 x 32 partials -> 32 stats (deterministic, no atomics)
__global__ __launch_bounds__(256) void reduce_stats_k(const float* __restrict__ bstats,
                                                      float* __restrict__ stats) {
  __shared__ float acc[8][32];
  const int c = threadIdx.x & 31, part = threadIdx.x >> 5;
  float s = 0;
  for (int b = part; b < 512; b += 8) s += bstats[b * 32 + c];
  acc[part][c] = s;
  __syncthreads();
  if (threadIdx.x < 32) {
    float t = 0;
#pragma unroll
    for (int p = 0; p < 8; ++p) t += acc[p][threadIdx.x];
    stats[threadIdx.x] = t;
  }
}

// ---- Encoder pass B: conv + BN + relu + maxpool + avgpool + FC -> s0 ----
__global__ __launch_bounds__(256) void enc_finish(const float* __restrict__ x,
                                                  const float* __restrict__ cw,
                                                  const float* __restrict__ stats,
                                                  const float* __restrict__ gamma,
                                                  const float* __restrict__ beta,
                                                  const float* __restrict__ fcw,
                                                  const float* __restrict__ fcb,
                                                  __hip_bfloat16* __restrict__ spb,
                                                  float* __restrict__ out) {
  __shared__ float imgp[2 * 66 * 66];
  __shared__ float red[4][16];
  __shared__ float plds[16];
  const int b = blockIdx.x, tid = threadIdx.x;
  for (int i = tid; i < 2 * 66 * 66; i += 256) imgp[i] = 0.0f;
  __syncthreads();
  const float* xb = x + b * 8192;
  for (int i = tid; i < 8192; i += 256) {
    int ci = i >> 12, rem = i & 4095, y = rem >> 6, xx = rem & 63;
    imgp[ci * 4356 + (y + 1) * 66 + (xx + 1)] = xb[i];
  }
  __syncthreads();

  const float invN = 1.0f / (512.0f * 4096.0f);
  const int wv = tid >> 6;

  for (int c4 = 0; c4 < 4; ++c4) {
    float w0[18], w1[18], w2[18], w3[18];
#pragma unroll
    for (int k = 0; k < 18; ++k) {
      w0[k] = cw[(c4 * 4 + 0) * 18 + k];
      w1[k] = cw[(c4 * 4 + 1) * 18 + k];
      w2[k] = cw[(c4 * 4 + 2) * 18 + k];
      w3[k] = cw[(c4 * 4 + 3) * 18 + k];
    }
    float sc0, sc1, sc2, sc3, sh0, sh1, sh2, sh3;
    {
      int c = c4 * 4 + 0; float m = stats[c] * invN; float var = stats[16 + c] * invN - m * m;
      float isd = rsqrtf(var + 1e-5f); sc0 = gamma[c] * isd; sh0 = beta[c] - m * sc0;
      c = c4 * 4 + 1; m = stats[c] * invN; var = stats[16 + c] * invN - m * m;
      isd = rsqrtf(var + 1e-5f); sc1 = gamma[c] * isd; sh1 = beta[c] - m * sc1;
      c = c4 * 4 + 2; m = stats[c] * invN; var = stats[16 + c] * invN - m * m;
      isd = rsqrtf(var + 1e-5f); sc2 = gamma[c] * isd; sh2 = beta[c] - m * sc2;
      c = c4 * 4 + 3; m = stats[c] * invN; var = stats[16 + c] * invN - m * m;
      isd = rsqrtf(var + 1e-5f); sc3 = gamma[c] * isd; sh3 = beta[c] - m * sc3;
    }
    float p0 = 0, p1 = 0, p2 = 0, p3 = 0;
    for (int q = tid; q < 1024; q += 256) {
      int py = q >> 5, px = q & 31;
      float m0 = 0, m1 = 0, m2 = 0, m3 = 0;
#pragma unroll
      for (int sy = 0; sy < 2; ++sy)
#pragma unroll
        for (int sx = 0; sx < 2; ++sx) {
          int y = 2 * py + sy, xx = 2 * px + sx;
          float v[18];
#pragma unroll
          for (int ci = 0; ci < 2; ++ci)
#pragma unroll
            for (int dy = 0; dy < 3; ++dy)
#pragma unroll
              for (int dx = 0; dx < 3; ++dx)
                v[ci * 9 + dy * 3 + dx] = imgp[ci * 4356 + (y + dy) * 66 + (xx + dx)];
          float a0 = 0, a1 = 0, a2 = 0, a3 = 0;
#pragma unroll
          for (int k = 0; k < 18; ++k) {
            a0 = fmaf(w0[k], v[k], a0);
            a1 = fmaf(w1[k], v[k], a1);
            a2 = fmaf(w2[k], v[k], a2);
            a3 = fmaf(w3[k], v[k], a3);
          }
          m0 = fmaxf(m0, fmaxf(fmaf(a0, sc0, sh0), 0.0f));
          m1 = fmaxf(m1, fmaxf(fmaf(a1, sc1, sh1), 0.0f));
          m2 = fmaxf(m2, fmaxf(fmaf(a2, sc2, sh2), 0.0f));
          m3 = fmaxf(m3, fmaxf(fmaf(a3, sc3, sh3), 0.0f));
        }
      p0 += m0; p1 += m1; p2 += m2; p3 += m3;
    }
#pragma unroll
    for (int off = 32; off >= 1; off >>= 1) {
      p0 += __shfl_down(p0, off);
      p1 += __shfl_down(p1, off);
      p2 += __shfl_down(p2, off);
      p3 += __shfl_down(p3, off);
    }
    if ((tid & 63) == 0) {
      red[wv][c4 * 4 + 0] = p0;
      red[wv][c4 * 4 + 1] = p1;
      red[wv][c4 * 4 + 2] = p2;
      red[wv][c4 * 4 + 3] = p3;
    }
  }
  __syncthreads();
  if (tid < 16)
    plds[tid] = (red[0][tid] + red[1][tid] + red[2][tid] + red[3][tid]) * (1.0f / 1024.0f);
  __syncthreads();

  float acc = fcb[tid];
#pragma unroll
  for (int c = 0; c < 16; ++c) acc = fmaf(plds[c], fcw[tid * 16 + c], acc);
  spb[b * 256 + tid] = __float2bfloat16(acc);
  out[(b * TT + 0) * 256 + tid] = acc;
}

// ------------- GRU step via bf16 MFMA: 32 rows x 32 hid-cols x 3 gates per block -------------
// 4 waves: wave w -> row-half m=w&1 (16 rows), col-half t=w>>1 (16 cols), 3 gate tiles.
__global__ __launch_bounds__(256) void gru_mfma(
    const __hip_bfloat16* __restrict__ spb,    // 512x256
    const __hip_bfloat16* __restrict__ hb_in,  // 512x512
    const float* __restrict__ h_in,            // 512x512 fp32
    float* __restrict__ h_out,
    __hip_bfloat16* __restrict__ hb_out,
    const __hip_bfloat16* __restrict__ wihb,   // 1536x256
    const __hip_bfloat16* __restrict__ whhb,   // 1536x512
    const float* __restrict__ wih,             // 1536x258 fp32 (u-tail cols 256,257)
    const float* __restrict__ actions,         // 512x16x2
    const float* __restrict__ bih, const float* __restrict__ bhh, int t) {
  const int tid = threadIdx.x;
  const int w = tid >> 6, lane = tid & 63;
  const int l15 = lane & 15, hi = lane >> 4;
  const int m = w & 1, tc = w >> 1;
  const int row0 = blockIdx.y * 32 + m * 16;
  const int cj = blockIdx.x * 32 + tc * 16;

  f32x4 aR = {0.f, 0.f, 0.f, 0.f}, aZ = aR, aXN = aR, aHN = aR;

  // phase 1: K=256 over s_prev
  {
    const __hip_bfloat16* ap = spb + (row0 + l15) * 256 + hi * 8;
    const __hip_bfloat16* bR = wihb + (cj + l15) * 256 + hi * 8;
    const __hip_bfloat16* bZ = wihb + (512 + cj + l15) * 256 + hi * 8;
    const __hip_bfloat16* bN = wihb + (1024 + cj + l15) * 256 + hi * 8;
#pragma unroll
    for (int k0 = 0; k0 < 256; k0 += 32) {
      bf16x8 a = *(const bf16x8*)(ap + k0);
      aR = __builtin_amdgcn_mfma_f32_16x16x32_bf16(a, *(const bf16x8*)(bR + k0), aR, 0, 0, 0);
      aZ = __builtin_amdgcn_mfma_f32_16x16x32_bf16(a, *(const bf16x8*)(bZ + k0), aZ, 0, 0, 0);
      aXN = __builtin_amdgcn_mfma_f32_16x16x32_bf16(a, *(const bf16x8*)(bN + k0), aXN, 0, 0, 0);
    }
  }
  // phase 2: K=512 over h
  {
    const __hip_bfloat16* ap = hb_in + (row0 + l15) * 512 + hi * 8;
    const __hip_bfloat16* bR = whhb + (cj + l15) * 512 + hi * 8;
    const __hip_bfloat16* bZ = whhb + (512 + cj + l15) * 512 + hi * 8;
    const __hip_bfloat16* bN = whhb + (1024 + cj + l15) * 512 + hi * 8;
#pragma unroll
    for (int k0 = 0; k0 < 512; k0 += 32) {
      bf16x8 a = *(const bf16x8*)(ap + k0);
      aR = __builtin_amdgcn_mfma_f32_16x16x32_bf16(a, *(const bf16x8*)(bR + k0), aR, 0, 0, 0);
      aZ = __builtin_amdgcn_mfma_f32_16x16x32_bf16(a, *(const bf16x8*)(bZ + k0), aZ, 0, 0, 0);
      aHN = __builtin_amdgcn_mfma_f32_16x16x32_bf16(a, *(const bf16x8*)(bN + k0), aHN, 0, 0, 0);
    }
  }
  // epilogue (fp32): biases + action tail + gates + blend
  const int col = cj + l15;
  const float br = bih[col] + bhh[col];
  const float bz = bih[512 + col] + bhh[512 + col];
  const float bxn = bih[1024 + col];
  const float bhn = bhh[1024 + col];
  const float wur = wih[col * 258 + 256], wvr = wih[col * 258 + 257];
  const float wuz = wih[(512 + col) * 258 + 256], wvz = wih[(512 + col) * 258 + 257];
  const float wun = wih[(1024 + col) * 258 + 256], wvn = wih[(1024 + col) * 258 + 257];
#pragma unroll
  for (int i = 0; i < 4; ++i) {
    const int r = row0 + hi * 4 + i;  // C/D layout: row=(lane>>4)*4+reg, col=lane&15
    const float u0 = actions[r * 32 + t * 2 + 0];
    const float u1 = actions[r * 32 + t * 2 + 1];
    const float gr = aR[i] + br + u0 * wur + u1 * wvr;
    const float gz = aZ[i] + bz + u0 * wuz + u1 * wvz;
    const float gxn = aXN[i] + bxn + u0 * wun + u1 * wvn;
    const float ghn = aHN[i] + bhn;
    const float rg = 1.0f / (1.0f + __expf(-gr));
    const float zg = 1.0f / (1.0f + __expf(-gz));
    float xn = gxn + rg * ghn;
    xn = fminf(fmaxf(xn, -15.0f), 15.0f);
    const float e = __expf(2.0f * xn);
    const float ng = (e - 1.0f) / (e + 1.0f);
    const float hp = h_in[r * 512 + col];
    const float hn = (1.0f - zg) * ng + zg * hp;
    h_out[r * 512 + col] = hn;
    hb_out[r * 512 + col] = __float2bfloat16(hn);
  }
}

// ------------------- pred FC via bf16 MFMA: 32x32 per block -------------------
__global__ __launch_bounds__(256) void pred_mfma(const __hip_bfloat16* __restrict__ hb,
                                                 const __hip_bfloat16* __restrict__ pwb,
                                                 const float* __restrict__ pb,
                                                 float* __restrict__ out,
                                                 __hip_bfloat16* __restrict__ spb, int t) {
  const int tid = threadIdx.x;
  const int w = tid >> 6, lane = tid & 63;
  const int l15 = lane & 15, hi = lane >> 4;
  const int row0 = blockIdx.y * 32 + (w & 1) * 16;
  const int cj = blockIdx.x * 32 + (w >> 1) * 16;
  f32x4 acc = {0.f, 0.f, 0.f, 0.f};
  const __hip_bfloat16* ap = hb + (row0 + l15) * 512 + hi * 8;
  const __hip_bfloat16* bp = pwb + (cj + l15) * 512 + hi * 8;
#pragma unroll
  for (int k0 = 0; k0 < 512; k0 += 32) {
    acc = __builtin_amdgcn_mfma_f32_16x16x32_bf16(*(const bf16x8*)(ap + k0),
                                                  *(const bf16x8*)(bp + k0), acc, 0, 0, 0);
  }
  const int col = cj + l15;
  const float bias = pb[col];
#pragma unroll
  for (int i = 0; i < 4; ++i) {
    const int r = row0 + hi * 4 + i;
    const float v = fmaxf(acc[i] + bias, 0.0f);
    out[(r * TT + t + 1) * 256 + col] = v;
    spb[r * 256 + col] = __float2bfloat16(v);
  }
}

extern "C" void kernel_launch(void* const* d_in, const int* in_sizes, int n_in,
                              void* d_out, int out_size, void* d_ws, size_t ws_size,
                              hipStream_t stream) {
  const float* x       = (const float*)d_in[0];
  const float* actions = (const float*)d_in[1];
  const float* cw      = (const float*)d_in[2];
  const float* gamma   = (const float*)d_in[3];
  const float* beta    = (const float*)d_in[4];
  const float* fcw     = (const float*)d_in[5];
  const float* fcb     = (const float*)d_in[6];
  const float* wih     = (const float*)d_in[7];
  const float* whh     = (const float*)d_in[8];
  const float* bih     = (const float*)d_in[9];
  const float* bhh     = (const float*)d_in[10];
  const float* pw      = (const float*)d_in[11];
  const float* pb      = (const float*)d_in[12];
  float* out = (float*)d_out;
  float* ws  = (float*)d_ws;

  float* stats  = ws + OFF_STATS;
  float* bstats = ws + OFF_BSTATS;
  float* h0     = ws + OFF_H0;
  float* h1     = ws + OFF_H1;
  __hip_bfloat16* hb0  = (__hip_bfloat16*)(ws + OFF_HB0);
  __hip_bfloat16* hb1  = (__hip_bfloat16*)(ws + OFF_HB1);
  __hip_bfloat16* spb  = (__hip_bfloat16*)(ws + OFF_SPB);
  __hip_bfloat16* wihb = (__hip_bfloat16*)(ws + OFF_WIHB);
  __hip_bfloat16* whhb = (__hip_bfloat16*)(ws + OFF_WHHB);
  __hip_bfloat16* pwb  = (__hip_bfloat16*)(ws + OFF_PWB);

  // h0 (fp32) and hb0 (bf16, zeroed as float words) must start at 0
  zero2_k<<<dim3(256), dim3(256), 0, stream>>>(h0, 512 * 512, (float*)hb0, 512 * 512 / 2);
  prep_weights_k<<<dim3(512), dim3(256), 0, stream>>>(wih, whh, pw, wihb, whhb, pwb);
  enc_conv_stats<<<dim3(512), dim3(256), 0, stream>>>(x, cw, bstats);
  reduce_stats_k<<<dim3(1), dim3(256), 0, stream>>>(bstats, stats);
  enc_finish<<<dim3(512), dim3(256), 0, stream>>>(x, cw, stats, gamma, beta, fcw, fcb,
                                                  spb, out);
  for (int t = 0; t < TM1; ++t) {
    float* hi_f = (t & 1) ? h1 : h0;
    float* ho_f = (t & 1) ? h0 : h1;
    __hip_bfloat16* hbi = (t & 1) ? hb1 : hb0;
    __hip_bfloat16* hbo = (t & 1) ? hb0 : hb1;
    gru_mfma<<<dim3(16, 16), dim3(256), 0, stream>>>(spb, hbi, hi_f, ho_f, hbo,
                                                     wihb, whhb, wih, actions, bih, bhh, t);
    pred_mfma<<<dim3(8, 16), dim3(256), 0, stream>>>(hbo, pwb, pb, out, spb, t);
  }
}